// Round 1
// baseline (352.626 us; speedup 1.0000x reference)
//
#include <hip/hip_runtime.h>
#include <hip/hip_bf16.h>

#define B_  2
#define S_  2048
#define M_  64
#define D_  1024
#define T_  2112      // M_ + S_
#define H_  16
#define HD_ 64
#define BT_ (B_*T_)   // 4224
#define NEGBIG (-1e9f)

typedef float f32x4  __attribute__((ext_vector_type(4)));
typedef short short8 __attribute__((ext_vector_type(8)));
typedef __bf16 bf16x8 __attribute__((ext_vector_type(8)));

static __device__ __forceinline__ unsigned short bf16_of(float f) {
  __hip_bfloat16 h = __float2bfloat16(f);
  return __builtin_bit_cast(unsigned short, h);
}

static __device__ __forceinline__ f32x4 mfma_bf16(short8 a, short8 b, f32x4 c) {
  return __builtin_amdgcn_mfma_f32_16x16x32_bf16(
      __builtin_bit_cast(bf16x8, a), __builtin_bit_cast(bf16x8, b), c, 0, 0, 0);
}

// ---------------- cast / concat kernels ----------------

__global__ void k_build_x(const float* __restrict__ tokens,
                          const float* __restrict__ memory,
                          unsigned short* __restrict__ xb) {
  for (int i = blockIdx.x * blockDim.x + threadIdx.x; i < BT_ * D_;
       i += gridDim.x * blockDim.x) {
    int b = i / (T_ * D_);
    int rem = i - b * (T_ * D_);
    int t = rem / D_;
    int d = rem - t * D_;
    float v = (t < M_) ? memory[((size_t)b * M_ + t) * D_ + d]
                       : tokens[((size_t)b * S_ + (t - M_)) * D_ + d];
    xb[i] = bf16_of(v);
  }
}

__global__ void k_cast(const float* __restrict__ src,
                       unsigned short* __restrict__ dst, int n, float scale) {
  for (int i = blockIdx.x * blockDim.x + threadIdx.x; i < n;
       i += gridDim.x * blockDim.x) {
    dst[i] = bf16_of(src[i] * scale);
  }
}

// ---------------- shared GEMM core ----------------
// C[m][n] = sum_k A[m][k] * BT[n][k]; both A and BT row-major with row stride K.
// Block = 256 threads (4 waves). Tile 64(M) x 64(N), K-step 32.
// Wave w computes rows [w*16, w*16+16) x all 64 cols -> acc[4] frags.
// acc[n][r]: row = w*16 + (l>>4)*4 + r, col = n*16 + (l&15).
__device__ __forceinline__ void gemm_core(const unsigned short* __restrict__ A,
                                          const unsigned short* __restrict__ BT,
                                          int K, int m0, int n0, f32x4 acc[4]) {
  __shared__ __align__(16) unsigned short As[64][40];
  __shared__ __align__(16) unsigned short Bs[64][40];
  const int tid = threadIdx.x;
  const int w = tid >> 6, l = tid & 63;
  const int sr = tid >> 2, sc = (tid & 3) * 8;
  f32x4 z;
  z[0] = z[1] = z[2] = z[3] = 0.f;
  acc[0] = acc[1] = acc[2] = acc[3] = z;
  for (int k0 = 0; k0 < K; k0 += 32) {
    __syncthreads();
    *(short8*)&As[sr][sc] = *(const short8*)&A[(size_t)(m0 + sr) * K + k0 + sc];
    *(short8*)&Bs[sr][sc] = *(const short8*)&BT[(size_t)(n0 + sr) * K + k0 + sc];
    __syncthreads();
    short8 a = *(const short8*)&As[w * 16 + (l & 15)][(l >> 4) * 8];
#pragma unroll
    for (int n = 0; n < 4; n++) {
      short8 b = *(const short8*)&Bs[n * 16 + (l & 15)][(l >> 4) * 8];
      acc[n] = mfma_bf16(a, b, acc[n]);
    }
  }
}

// ---------------- QKV projection ----------------
// grid: x = n-tile (16), y = m-tile (66), z = which (0=q,1=k,2=v)
__global__ __launch_bounds__(256) void k_qkv(
    const unsigned short* __restrict__ xb, const unsigned short* __restrict__ Wqb,
    const unsigned short* __restrict__ Wkb, const unsigned short* __restrict__ Wvb,
    const float* __restrict__ bq, const float* __restrict__ bk,
    const float* __restrict__ bv, unsigned short* __restrict__ qg,
    unsigned short* __restrict__ kg, unsigned short* __restrict__ vTg) {
  const int z = blockIdx.z;
  const unsigned short* W = (z == 0) ? Wqb : ((z == 1) ? Wkb : Wvb);
  const float* bias = (z == 0) ? bq : ((z == 1) ? bk : bv);
  f32x4 acc[4];
  gemm_core(xb, W, D_, blockIdx.y * 64, blockIdx.x * 64, acc);
  const int tid = threadIdx.x, w = tid >> 6, l = tid & 63;
#pragma unroll
  for (int n = 0; n < 4; n++) {
#pragma unroll
    for (int r = 0; r < 4; r++) {
      int m = blockIdx.y * 64 + w * 16 + (l >> 4) * 4 + r;
      int c = blockIdx.x * 64 + n * 16 + (l & 15);
      int b = m / T_, t = m - b * T_;
      int h = c >> 6, dh = c & 63;
      int bh = b * H_ + h;
      float v = acc[n][r] + bias[c];
      if (z == 0)
        qg[((size_t)bh * T_ + t) * HD_ + dh] = bf16_of(v * 0.125f);
      else if (z == 1)
        kg[((size_t)bh * T_ + t) * HD_ + dh] = bf16_of(v);
      else
        vTg[((size_t)bh * HD_ + dh) * T_ + t] = bf16_of(v);
    }
  }
}

// ---------------- fused attention ----------------
// grid: x = q-tile (33), y = bh (32). 4 waves; wave w owns q-rows [qt*64+w*16, +16).
__global__ __launch_bounds__(256) void k_attn(
    const unsigned short* __restrict__ qg, const unsigned short* __restrict__ kg,
    const unsigned short* __restrict__ vTg, unsigned short* __restrict__ ctx) {
  const int qt = blockIdx.x;
  const int bh = blockIdx.y;
  const int tid = threadIdx.x, w = tid >> 6, l = tid & 63;
  __shared__ __align__(16) unsigned short Ks[64][72];
  __shared__ __align__(16) unsigned short Vs[64][72];
  __shared__ __align__(16) unsigned short Ps[4][16][72];
  const unsigned short* qb = qg + (size_t)bh * T_ * HD_;
  const unsigned short* kb = kg + (size_t)bh * T_ * HD_;
  const unsigned short* vb = vTg + (size_t)bh * HD_ * T_;

  // q fragments for this wave's 16 rows (hd = 64 -> 2 K-steps)
  short8 aq[2];
  const int qrow = qt * 64 + w * 16 + (l & 15);
#pragma unroll
  for (int s = 0; s < 2; s++)
    aq[s] = *(const short8*)&qb[(size_t)qrow * HD_ + s * 32 + (l >> 4) * 8];

  f32x4 o[4];
  f32x4 zz; zz[0] = zz[1] = zz[2] = zz[3] = 0.f;
  o[0] = o[1] = o[2] = o[3] = zz;
  float mrun[4], lrun[4];
#pragma unroll
  for (int r = 0; r < 4; r++) { mrun[r] = -1e30f; lrun[r] = 0.f; }

  const int nkt = (qt == 0) ? (T_ / 64) : (qt + 1);
  const int str = tid >> 3, stc = (tid & 7) * 8;  // staging: 32 rows/pass, 2 passes
  for (int j = 0; j < nkt; j++) {
    __syncthreads();
#pragma unroll
    for (int p = 0; p < 2; p++) {
      int rr = p * 32 + str;
      *(short8*)&Ks[rr][stc] = *(const short8*)&kb[((size_t)(j * 64 + rr)) * HD_ + stc];
      *(short8*)&Vs[rr][stc] = *(const short8*)&vb[(size_t)rr * T_ + j * 64 + stc];
    }
    __syncthreads();

    // S = q * k^T (scale already folded into q)
    f32x4 s[4];
    s[0] = s[1] = s[2] = s[3] = zz;
#pragma unroll
    for (int st = 0; st < 2; st++) {
#pragma unroll
      for (int n = 0; n < 4; n++) {
        short8 bk = *(const short8*)&Ks[n * 16 + (l & 15)][st * 32 + (l >> 4) * 8];
        s[n] = mfma_bf16(aq[st], bk, s[n]);
      }
    }
    // causal mask on the diagonal tile (token rows only; qt==0 is memory rows)
    if (qt > 0 && j == qt) {
#pragma unroll
      for (int n = 0; n < 4; n++) {
#pragma unroll
        for (int r = 0; r < 4; r++) {
          int t1l = w * 16 + (l >> 4) * 4 + r;
          int t2l = n * 16 + (l & 15);
          if (t2l > t1l) s[n][r] = NEGBIG;
        }
      }
    }
    // row max (row lives across the 16 lanes of each l>>4 group)
    float pm[4];
#pragma unroll
    for (int r = 0; r < 4; r++) {
      pm[r] = fmaxf(fmaxf(s[0][r], s[1][r]), fmaxf(s[2][r], s[3][r]));
#pragma unroll
      for (int mk = 1; mk < 16; mk <<= 1) pm[r] = fmaxf(pm[r], __shfl_xor(pm[r], mk));
    }
    float fac[4];
#pragma unroll
    for (int r = 0; r < 4; r++) {
      float mn = fmaxf(mrun[r], pm[r]);
      fac[r] = __expf(mrun[r] - mn);
      mrun[r] = mn;
    }
    // P = exp(S - m), row sums, stash P (bf16) in LDS for the PV MFMA
    float rsum[4] = {0.f, 0.f, 0.f, 0.f};
#pragma unroll
    for (int n = 0; n < 4; n++) {
#pragma unroll
      for (int r = 0; r < 4; r++) {
        float p = __expf(s[n][r] - mrun[r]);
        s[n][r] = p;
        rsum[r] += p;
      }
    }
#pragma unroll
    for (int r = 0; r < 4; r++) {
#pragma unroll
      for (int mk = 1; mk < 16; mk <<= 1) rsum[r] += __shfl_xor(rsum[r], mk);
      lrun[r] = lrun[r] * fac[r] + rsum[r];
    }
#pragma unroll
    for (int n = 0; n < 4; n++)
#pragma unroll
      for (int r = 0; r < 4; r++) o[n][r] *= fac[r];
#pragma unroll
    for (int n = 0; n < 4; n++)
#pragma unroll
      for (int r = 0; r < 4; r++)
        Ps[w][(l >> 4) * 4 + r][n * 16 + (l & 15)] = bf16_of(s[n][r]);

    // O += P * V   (A = P 16x64, B = V 64x64 via vT rows)
#pragma unroll
    for (int st = 0; st < 2; st++) {
      short8 ap = *(const short8*)&Ps[w][l & 15][st * 32 + (l >> 4) * 8];
#pragma unroll
      for (int n = 0; n < 4; n++) {
        short8 bv = *(const short8*)&Vs[n * 16 + (l & 15)][st * 32 + (l >> 4) * 8];
        o[n] = mfma_bf16(ap, bv, o[n]);
      }
    }
  }
  // epilogue: ctx (bf16) in (B,T,D) with D index = h*64 + dh
  const int b = bh >> 4, h = bh & 15;
#pragma unroll
  for (int n = 0; n < 4; n++) {
#pragma unroll
    for (int r = 0; r < 4; r++) {
      float val = o[n][r] / lrun[r];
      int t = qt * 64 + w * 16 + (l >> 4) * 4 + r;
      int dg = h * HD_ + n * 16 + (l & 15);
      ctx[((size_t)(b * T_ + t)) * D_ + dg] = bf16_of(val);
    }
  }
}

// ---------------- output projection + residual + splits ----------------
// grid: x = n-tile (16), y = m-tile (66)
__global__ __launch_bounds__(256) void k_out(
    const unsigned short* __restrict__ ctxb, const unsigned short* __restrict__ Wob,
    const float* __restrict__ bo, const float* __restrict__ tokens,
    const float* __restrict__ memory, float* __restrict__ out_tok,
    unsigned short* __restrict__ tokb, unsigned short* __restrict__ tokTb,
    float* __restrict__ memout, unsigned short* __restrict__ comb) {
  f32x4 acc[4];
  gemm_core(ctxb, Wob, D_, blockIdx.y * 64, blockIdx.x * 64, acc);
  const int tid = threadIdx.x, w = tid >> 6, l = tid & 63;
#pragma unroll
  for (int n = 0; n < 4; n++) {
#pragma unroll
    for (int r = 0; r < 4; r++) {
      int m = blockIdx.y * 64 + w * 16 + (l >> 4) * 4 + r;
      int c = blockIdx.x * 64 + n * 16 + (l & 15);
      int b = m / T_, t = m - b * T_;
      float xo = (t < M_) ? memory[((size_t)b * M_ + t) * D_ + c]
                          : tokens[((size_t)b * S_ + (t - M_)) * D_ + c];
      float val = acc[n][r] + bo[c] + xo;
      if (t < M_) {
        memout[((size_t)b * M_ + t) * D_ + c] = val;
        comb[((size_t)b * M_ + t) * (2 * D_) + c] = bf16_of(val);
      } else {
        size_t ti = (size_t)b * S_ + (t - M_);
        out_tok[ti * D_ + c] = val;
        tokb[ti * D_ + c] = bf16_of(val);
        tokTb[((size_t)b * D_ + c) * S_ + (t - M_)] = bf16_of(val);
      }
    }
  }
}

// ---------------- pool scores ----------------
// grid: x = s-tile (32), z = b.  A = pool_q (64x1024, scale folded), BT = tok_out
__global__ __launch_bounds__(256) void k_pscore(
    const unsigned short* __restrict__ pqb, const unsigned short* __restrict__ tokb,
    float* __restrict__ pscores) {
  f32x4 acc[4];
  const unsigned short* Bt = tokb + (size_t)blockIdx.z * S_ * D_;
  gemm_core(pqb, Bt, D_, 0, blockIdx.x * 64, acc);
  const int tid = threadIdx.x, w = tid >> 6, l = tid & 63;
#pragma unroll
  for (int n = 0; n < 4; n++) {
#pragma unroll
    for (int r = 0; r < 4; r++) {
      int m = w * 16 + (l >> 4) * 4 + r;
      int s = blockIdx.x * 64 + n * 16 + (l & 15);
      pscores[((size_t)blockIdx.z * M_ + m) * S_ + s] = acc[n][r];
    }
  }
}

// ---------------- pool softmax (one block per (b,m) row) ----------------
__global__ __launch_bounds__(256) void k_psoftmax(const float* __restrict__ ps,
                                                  unsigned short* __restrict__ pw) {
  const int row = blockIdx.x;
  const float* src = ps + (size_t)row * S_;
  const int tid = threadIdx.x;
  float v[8];
  float mx = -1e30f;
#pragma unroll
  for (int i = 0; i < 8; i++) {
    v[i] = src[tid + i * 256];
    mx = fmaxf(mx, v[i]);
  }
#pragma unroll
  for (int off = 1; off < 64; off <<= 1) mx = fmaxf(mx, __shfl_xor(mx, off));
  __shared__ float rm[4], rs[4];
  if ((tid & 63) == 0) rm[tid >> 6] = mx;
  __syncthreads();
  mx = fmaxf(fmaxf(rm[0], rm[1]), fmaxf(rm[2], rm[3]));
  float sum = 0.f;
#pragma unroll
  for (int i = 0; i < 8; i++) {
    v[i] = __expf(v[i] - mx);
    sum += v[i];
  }
#pragma unroll
  for (int off = 1; off < 64; off <<= 1) sum += __shfl_xor(sum, off);
  if ((tid & 63) == 0) rs[tid >> 6] = sum;
  __syncthreads();
  float inv = 1.f / (rs[0] + rs[1] + rs[2] + rs[3]);
#pragma unroll
  for (int i = 0; i < 8; i++)
    pw[(size_t)row * S_ + tid + i * 256] = bf16_of(v[i] * inv);
}

// ---------------- summary = pweights @ tok_out -> combined[:, D:] ----------------
// grid: x = d-tile (16), z = b.  A = pweights (64xS), BT = tokT (D x S)
__global__ __launch_bounds__(256) void k_summary(
    const unsigned short* __restrict__ pw, const unsigned short* __restrict__ tokTb,
    unsigned short* __restrict__ comb) {
  f32x4 acc[4];
  const int b = blockIdx.z;
  gemm_core(pw + (size_t)b * M_ * S_, tokTb + (size_t)b * D_ * S_, S_, 0,
            blockIdx.x * 64, acc);
  const int tid = threadIdx.x, w = tid >> 6, l = tid & 63;
#pragma unroll
  for (int n = 0; n < 4; n++) {
#pragma unroll
    for (int r = 0; r < 4; r++) {
      int m = w * 16 + (l >> 4) * 4 + r;
      int c = blockIdx.x * 64 + n * 16 + (l & 15);
      comb[((size_t)b * M_ + m) * (2 * D_) + D_ + c] = bf16_of(acc[n][r]);
    }
  }
}

// ---------------- cell GEMM: update = combined @ cell_W^T + cell_b ----------------
// grid: x = n-tile (32), y = m-tile (2) over B*M = 128 rows
__global__ __launch_bounds__(256) void k_cell(
    const unsigned short* __restrict__ comb, const unsigned short* __restrict__ cWb,
    const float* __restrict__ cb, float* __restrict__ update) {
  f32x4 acc[4];
  gemm_core(comb, cWb, 2 * D_, blockIdx.y * 64, blockIdx.x * 64, acc);
  const int tid = threadIdx.x, w = tid >> 6, l = tid & 63;
#pragma unroll
  for (int n = 0; n < 4; n++) {
#pragma unroll
    for (int r = 0; r < 4; r++) {
      int m = blockIdx.y * 64 + w * 16 + (l >> 4) * 4 + r;
      int c = blockIdx.x * 64 + n * 16 + (l & 15);
      update[(size_t)m * (2 * D_) + c] = acc[n][r] + cb[c];
    }
  }
}

// ---------------- final gating ----------------
__global__ void k_newmem(const float* __restrict__ update,
                         const float* __restrict__ memout,
                         float* __restrict__ out2) {
  int i = blockIdx.x * blockDim.x + threadIdx.x;
  if (i >= B_ * M_ * D_) return;
  int r = i >> 10, d = i & 1023;
  float g = update[(size_t)r * (2 * D_) + d];
  float c = update[(size_t)r * (2 * D_) + D_ + d];
  float sg = 1.f / (1.f + __expf(-g));
  float sc = 1.f / (1.f + __expf(-c));
  out2[i] = memout[i] * sg + (1.f - sg) * (c * sc);
}

// ---------------- launch ----------------
extern "C" void kernel_launch(void* const* d_in, const int* in_sizes, int n_in,
                              void* d_out, int out_size, void* d_ws, size_t ws_size,
                              hipStream_t stream) {
  const float* tokens = (const float*)d_in[0];
  const float* memory = (const float*)d_in[1];
  const float* Wq = (const float*)d_in[2];
  const float* bq = (const float*)d_in[3];
  const float* Wk = (const float*)d_in[4];
  const float* bk = (const float*)d_in[5];
  const float* Wv = (const float*)d_in[6];
  const float* bv = (const float*)d_in[7];
  const float* Wo = (const float*)d_in[8];
  const float* bo = (const float*)d_in[9];
  const float* pool_q = (const float*)d_in[10];
  const float* cell_W = (const float*)d_in[11];
  const float* cell_b = (const float*)d_in[12];

  size_t off = 0;
  auto alloc = [&](size_t bytes) -> void* {
    void* p = (char*)d_ws + off;
    off += (bytes + 255) & ~(size_t)255;
    return p;
  };
  unsigned short* xb    = (unsigned short*)alloc((size_t)BT_ * D_ * 2);
  unsigned short* Wqb   = (unsigned short*)alloc((size_t)D_ * D_ * 2);
  unsigned short* Wkb   = (unsigned short*)alloc((size_t)D_ * D_ * 2);
  unsigned short* Wvb   = (unsigned short*)alloc((size_t)D_ * D_ * 2);
  unsigned short* Wob   = (unsigned short*)alloc((size_t)D_ * D_ * 2);
  unsigned short* cWb   = (unsigned short*)alloc((size_t)(2 * D_) * (2 * D_) * 2);
  unsigned short* pqb   = (unsigned short*)alloc((size_t)M_ * D_ * 2);
  unsigned short* qg    = (unsigned short*)alloc((size_t)B_ * H_ * T_ * HD_ * 2);
  unsigned short* kg    = (unsigned short*)alloc((size_t)B_ * H_ * T_ * HD_ * 2);
  unsigned short* vTg   = (unsigned short*)alloc((size_t)B_ * H_ * HD_ * T_ * 2);
  unsigned short* ctxb  = (unsigned short*)alloc((size_t)BT_ * D_ * 2);
  unsigned short* tokb  = (unsigned short*)alloc((size_t)B_ * S_ * D_ * 2);
  unsigned short* tokTb = (unsigned short*)alloc((size_t)B_ * D_ * S_ * 2);
  float*          memout= (float*)alloc((size_t)B_ * M_ * D_ * 4);
  unsigned short* comb  = (unsigned short*)alloc((size_t)B_ * M_ * 2 * D_ * 2);
  float*          pscor = (float*)alloc((size_t)B_ * M_ * S_ * 4);
  unsigned short* pwt   = (unsigned short*)alloc((size_t)B_ * M_ * S_ * 2);
  float*          upd   = (float*)alloc((size_t)B_ * M_ * 2 * D_ * 4);

  float* out_tok = (float*)d_out;
  float* out_mem = out_tok + (size_t)B_ * S_ * D_;

  k_build_x<<<2048, 256, 0, stream>>>(tokens, memory, xb);
  k_cast<<<1024, 256, 0, stream>>>(Wq, Wqb, D_ * D_, 1.f);
  k_cast<<<1024, 256, 0, stream>>>(Wk, Wkb, D_ * D_, 1.f);
  k_cast<<<1024, 256, 0, stream>>>(Wv, Wvb, D_ * D_, 1.f);
  k_cast<<<1024, 256, 0, stream>>>(Wo, Wob, D_ * D_, 1.f);
  k_cast<<<2048, 256, 0, stream>>>(cell_W, cWb, 4 * D_ * D_, 1.f);
  k_cast<<<64, 256, 0, stream>>>(pool_q, pqb, M_ * D_, 0.03125f);  // D^-0.5

  k_qkv<<<dim3(16, 66, 3), 256, 0, stream>>>(xb, Wqb, Wkb, Wvb, bq, bk, bv, qg, kg, vTg);
  k_attn<<<dim3(33, 32), 256, 0, stream>>>(qg, kg, vTg, ctxb);
  k_out<<<dim3(16, 66), 256, 0, stream>>>(ctxb, Wob, bo, tokens, memory, out_tok,
                                          tokb, tokTb, memout, comb);
  k_pscore<<<dim3(32, 1, 2), 256, 0, stream>>>(pqb, tokb, pscor);
  k_psoftmax<<<B_ * M_, 256, 0, stream>>>(pscor, pwt);
  k_summary<<<dim3(16, 1, 2), 256, 0, stream>>>(pwt, tokTb, comb);
  k_cell<<<dim3(32, 2), 256, 0, stream>>>(comb, cWb, cell_b, upd);
  k_newmem<<<512, 256, 0, stream>>>(upd, memout, out_mem);
}

// Round 2
// 320.132 us; speedup vs baseline: 1.1015x; 1.1015x over previous
//
#include <hip/hip_runtime.h>
#include <hip/hip_bf16.h>

#define B_  2
#define S_  2048
#define M_  64
#define D_  1024
#define T_  2112      // M_ + S_
#define H_  16
#define HD_ 64
#define BT_ (B_*T_)   // 4224
#define NEGBIG (-1e9f)

typedef float f32x4  __attribute__((ext_vector_type(4)));
typedef short short8 __attribute__((ext_vector_type(8)));
typedef __bf16 bf16x8 __attribute__((ext_vector_type(8)));

static __device__ __forceinline__ unsigned short bf16_of(float f) {
  __hip_bfloat16 h = __float2bfloat16(f);
  return __builtin_bit_cast(unsigned short, h);
}

static __device__ __forceinline__ f32x4 mfma_bf16(short8 a, short8 b, f32x4 c) {
  return __builtin_amdgcn_mfma_f32_16x16x32_bf16(
      __builtin_bit_cast(bf16x8, a), __builtin_bit_cast(bf16x8, b), c, 0, 0, 0);
}

// async global->LDS, 16B per lane; lds base must be wave-uniform.
static __device__ __forceinline__ void gload16(const void* g, void* lds) {
  __builtin_amdgcn_global_load_lds(
      (const __attribute__((address_space(1))) unsigned int*)g,
      (__attribute__((address_space(3))) unsigned int*)lds, 16, 0, 0);
}

// ---------------- cast / concat kernels ----------------

__global__ void k_build_x(const float* __restrict__ tokens,
                          const float* __restrict__ memory,
                          unsigned short* __restrict__ xb) {
  for (int i = blockIdx.x * blockDim.x + threadIdx.x; i < BT_ * D_;
       i += gridDim.x * blockDim.x) {
    int b = i / (T_ * D_);
    int rem = i - b * (T_ * D_);
    int t = rem / D_;
    int d = rem - t * D_;
    float v = (t < M_) ? memory[((size_t)b * M_ + t) * D_ + d]
                       : tokens[((size_t)b * S_ + (t - M_)) * D_ + d];
    xb[i] = bf16_of(v);
  }
}

// one launch casts: Wq,Wk,Wv,Wo (4 x 1M), cell_W (4M), pool_q (64K, scaled)
__global__ void k_cast_all(const float* __restrict__ Wq, const float* __restrict__ Wk,
                           const float* __restrict__ Wv, const float* __restrict__ Wo,
                           const float* __restrict__ cW, const float* __restrict__ pq,
                           unsigned short* __restrict__ Wqb, unsigned short* __restrict__ Wkb,
                           unsigned short* __restrict__ Wvb, unsigned short* __restrict__ Wob,
                           unsigned short* __restrict__ cWb, unsigned short* __restrict__ pqb) {
  const int NW = D_ * D_;            // 1M
  const int NC = 4 * D_ * D_;        // 4M
  const int NP = M_ * D_;            // 64K
  const int total = 4 * NW + NC + NP;
  for (int i = blockIdx.x * blockDim.x + threadIdx.x; i < total;
       i += gridDim.x * blockDim.x) {
    if (i < 4 * NW) {
      int which = i >> 20, j = i & (NW - 1);
      const float* s = (which == 0) ? Wq : (which == 1) ? Wk : (which == 2) ? Wv : Wo;
      unsigned short* d = (which == 0) ? Wqb : (which == 1) ? Wkb : (which == 2) ? Wvb : Wob;
      d[j] = bf16_of(s[j]);
    } else if (i < 4 * NW + NC) {
      int j = i - 4 * NW;
      cWb[j] = bf16_of(cW[j]);
    } else {
      int j = i - 4 * NW - NC;
      pqb[j] = bf16_of(pq[j] * 0.03125f);   // D^-0.5
    }
  }
}

// ---------------- 128x128 GEMM core (m97 structure) ----------------
// C[m][n] = sum_k A[m][k] * BT[n][k]; A,BT row-major, row stride K (mult of 32).
// Block 256 = 4 waves; wave w owns 64x64 quadrant (wr=w>>1, wc=w&1), 4x4 frags.
// acc[i][j][r]: row = m0 + wr*64 + i*16 + (l>>4)*4 + r, col = n0 + wc*64 + j*16 + (l&15).
__device__ __forceinline__ void gemm128_core(const unsigned short* __restrict__ A,
                                             const unsigned short* __restrict__ BT,
                                             int K, int m0, int n0,
                                             f32x4 acc[4][4]) {
  __shared__ __align__(16) unsigned short As[128][32];
  __shared__ __align__(16) unsigned short Bs[128][32];
  const int tid = threadIdx.x;
  const int w = tid >> 6, l = tid & 63;
  const int wr = w >> 1, wc = w & 1;
  const int srow = l >> 2;          // row within 16-row staging chunk
  const int scol = (l & 3) * 8;     // element col within 32-wide K slab
  f32x4 z; z[0] = z[1] = z[2] = z[3] = 0.f;
#pragma unroll
  for (int i = 0; i < 4; i++)
#pragma unroll
    for (int j = 0; j < 4; j++) acc[i][j] = z;

  for (int k0 = 0; k0 < K; k0 += 32) {
    __syncthreads();
#pragma unroll
    for (int c = 0; c < 2; c++) {
      int rbase = w * 32 + c * 16;
      gload16(&A[(size_t)(m0 + rbase + srow) * K + k0 + scol], &As[rbase][0]);
      gload16(&BT[(size_t)(n0 + rbase + srow) * K + k0 + scol], &Bs[rbase][0]);
    }
    __syncthreads();
    short8 a[4], b[4];
#pragma unroll
    for (int i = 0; i < 4; i++)
      a[i] = *(const short8*)&As[wr * 64 + i * 16 + (l & 15)][(l >> 4) * 8];
#pragma unroll
    for (int j = 0; j < 4; j++)
      b[j] = *(const short8*)&Bs[wc * 64 + j * 16 + (l & 15)][(l >> 4) * 8];
#pragma unroll
    for (int i = 0; i < 4; i++)
#pragma unroll
      for (int j = 0; j < 4; j++)
        acc[i][j] = mfma_bf16(a[i], b[j], acc[i][j]);
  }
}

// ---------------- small 64x64 GEMM core (for low-parallelism GEMMs) ----------------
__device__ __forceinline__ void gemm_core(const unsigned short* __restrict__ A,
                                          const unsigned short* __restrict__ BT,
                                          int K, int m0, int n0, f32x4 acc[4]) {
  __shared__ __align__(16) unsigned short As[64][40];
  __shared__ __align__(16) unsigned short Bs[64][40];
  const int tid = threadIdx.x;
  const int w = tid >> 6, l = tid & 63;
  const int sr = tid >> 2, sc = (tid & 3) * 8;
  f32x4 z; z[0] = z[1] = z[2] = z[3] = 0.f;
  acc[0] = acc[1] = acc[2] = acc[3] = z;
  for (int k0 = 0; k0 < K; k0 += 32) {
    __syncthreads();
    *(short8*)&As[sr][sc] = *(const short8*)&A[(size_t)(m0 + sr) * K + k0 + sc];
    *(short8*)&Bs[sr][sc] = *(const short8*)&BT[(size_t)(n0 + sr) * K + k0 + sc];
    __syncthreads();
    short8 a = *(const short8*)&As[w * 16 + (l & 15)][(l >> 4) * 8];
#pragma unroll
    for (int n = 0; n < 4; n++) {
      short8 b = *(const short8*)&Bs[n * 16 + (l & 15)][(l >> 4) * 8];
      acc[n] = mfma_bf16(a, b, acc[n]);
    }
  }
}

// ---------------- QKV projection (128-tile) ----------------
// grid: x = n-tile (8), y = m-tile (33), z = which (0=q,1=k,2=v)
__global__ __launch_bounds__(256) void k_qkv(
    const unsigned short* __restrict__ xb, const unsigned short* __restrict__ Wqb,
    const unsigned short* __restrict__ Wkb, const unsigned short* __restrict__ Wvb,
    const float* __restrict__ bq, const float* __restrict__ bk,
    const float* __restrict__ bv, unsigned short* __restrict__ qg,
    unsigned short* __restrict__ kg, unsigned short* __restrict__ vTg) {
  const int z = blockIdx.z;
  const unsigned short* W = (z == 0) ? Wqb : ((z == 1) ? Wkb : Wvb);
  const float* bias = (z == 0) ? bq : ((z == 1) ? bk : bv);
  f32x4 acc[4][4];
  const int m0 = blockIdx.y * 128, n0 = blockIdx.x * 128;
  gemm128_core(xb, W, D_, m0, n0, acc);
  const int tid = threadIdx.x, w = tid >> 6, l = tid & 63;
  const int wr = w >> 1, wc = w & 1;
#pragma unroll
  for (int i = 0; i < 4; i++) {
#pragma unroll
    for (int j = 0; j < 4; j++) {
#pragma unroll
      for (int r = 0; r < 4; r++) {
        int m = m0 + wr * 64 + i * 16 + (l >> 4) * 4 + r;
        int c = n0 + wc * 64 + j * 16 + (l & 15);
        int b = m / T_, t = m - b * T_;
        int h = c >> 6, dh = c & 63;
        int bh = b * H_ + h;
        float v = acc[i][j][r] + bias[c];
        if (z == 0)
          qg[((size_t)bh * T_ + t) * HD_ + dh] = bf16_of(v * 0.125f);
        else if (z == 1)
          kg[((size_t)bh * T_ + t) * HD_ + dh] = bf16_of(v);
        else
          vTg[((size_t)bh * HD_ + dh) * T_ + t] = bf16_of(v);
      }
    }
  }
}

// ---------------- fused attention (unchanged this round) ----------------
// grid: x = q-tile (33), y = bh (32). 4 waves; wave w owns q-rows [qt*64+w*16, +16).
__global__ __launch_bounds__(256) void k_attn(
    const unsigned short* __restrict__ qg, const unsigned short* __restrict__ kg,
    const unsigned short* __restrict__ vTg, unsigned short* __restrict__ ctx) {
  const int qt = blockIdx.x;
  const int bh = blockIdx.y;
  const int tid = threadIdx.x, w = tid >> 6, l = tid & 63;
  __shared__ __align__(16) unsigned short Ks[64][72];
  __shared__ __align__(16) unsigned short Vs[64][72];
  __shared__ __align__(16) unsigned short Ps[4][16][72];
  const unsigned short* qb = qg + (size_t)bh * T_ * HD_;
  const unsigned short* kb = kg + (size_t)bh * T_ * HD_;
  const unsigned short* vb = vTg + (size_t)bh * HD_ * T_;

  short8 aq[2];
  const int qrow = qt * 64 + w * 16 + (l & 15);
#pragma unroll
  for (int s = 0; s < 2; s++)
    aq[s] = *(const short8*)&qb[(size_t)qrow * HD_ + s * 32 + (l >> 4) * 8];

  f32x4 o[4];
  f32x4 zz; zz[0] = zz[1] = zz[2] = zz[3] = 0.f;
  o[0] = o[1] = o[2] = o[3] = zz;
  float mrun[4], lrun[4];
#pragma unroll
  for (int r = 0; r < 4; r++) { mrun[r] = -1e30f; lrun[r] = 0.f; }

  const int nkt = (qt == 0) ? (T_ / 64) : (qt + 1);
  const int str = tid >> 3, stc = (tid & 7) * 8;
  for (int j = 0; j < nkt; j++) {
    __syncthreads();
#pragma unroll
    for (int p = 0; p < 2; p++) {
      int rr = p * 32 + str;
      *(short8*)&Ks[rr][stc] = *(const short8*)&kb[((size_t)(j * 64 + rr)) * HD_ + stc];
      *(short8*)&Vs[rr][stc] = *(const short8*)&vb[(size_t)rr * T_ + j * 64 + stc];
    }
    __syncthreads();

    f32x4 s[4];
    s[0] = s[1] = s[2] = s[3] = zz;
#pragma unroll
    for (int st = 0; st < 2; st++) {
#pragma unroll
      for (int n = 0; n < 4; n++) {
        short8 bk = *(const short8*)&Ks[n * 16 + (l & 15)][st * 32 + (l >> 4) * 8];
        s[n] = mfma_bf16(aq[st], bk, s[n]);
      }
    }
    if (qt > 0 && j == qt) {
#pragma unroll
      for (int n = 0; n < 4; n++) {
#pragma unroll
        for (int r = 0; r < 4; r++) {
          int t1l = w * 16 + (l >> 4) * 4 + r;
          int t2l = n * 16 + (l & 15);
          if (t2l > t1l) s[n][r] = NEGBIG;
        }
      }
    }
    float pm[4];
#pragma unroll
    for (int r = 0; r < 4; r++) {
      pm[r] = fmaxf(fmaxf(s[0][r], s[1][r]), fmaxf(s[2][r], s[3][r]));
#pragma unroll
      for (int mk = 1; mk < 16; mk <<= 1) pm[r] = fmaxf(pm[r], __shfl_xor(pm[r], mk));
    }
    float fac[4];
#pragma unroll
    for (int r = 0; r < 4; r++) {
      float mn = fmaxf(mrun[r], pm[r]);
      fac[r] = __expf(mrun[r] - mn);
      mrun[r] = mn;
    }
    float rsum[4] = {0.f, 0.f, 0.f, 0.f};
#pragma unroll
    for (int n = 0; n < 4; n++) {
#pragma unroll
      for (int r = 0; r < 4; r++) {
        float p = __expf(s[n][r] - mrun[r]);
        s[n][r] = p;
        rsum[r] += p;
      }
    }
#pragma unroll
    for (int r = 0; r < 4; r++) {
#pragma unroll
      for (int mk = 1; mk < 16; mk <<= 1) rsum[r] += __shfl_xor(rsum[r], mk);
      lrun[r] = lrun[r] * fac[r] + rsum[r];
    }
#pragma unroll
    for (int n = 0; n < 4; n++)
#pragma unroll
      for (int r = 0; r < 4; r++) o[n][r] *= fac[r];
#pragma unroll
    for (int n = 0; n < 4; n++)
#pragma unroll
      for (int r = 0; r < 4; r++)
        Ps[w][(l >> 4) * 4 + r][n * 16 + (l & 15)] = bf16_of(s[n][r]);

#pragma unroll
    for (int st = 0; st < 2; st++) {
      short8 ap = *(const short8*)&Ps[w][l & 15][st * 32 + (l >> 4) * 8];
#pragma unroll
      for (int n = 0; n < 4; n++) {
        short8 bv = *(const short8*)&Vs[n * 16 + (l & 15)][st * 32 + (l >> 4) * 8];
        o[n] = mfma_bf16(ap, bv, o[n]);
      }
    }
  }
  const int b = bh >> 4, h = bh & 15;
#pragma unroll
  for (int n = 0; n < 4; n++) {
#pragma unroll
    for (int r = 0; r < 4; r++) {
      float val = o[n][r] / lrun[r];
      int t = qt * 64 + w * 16 + (l >> 4) * 4 + r;
      int dg = h * HD_ + n * 16 + (l & 15);
      ctx[((size_t)(b * T_ + t)) * D_ + dg] = bf16_of(val);
    }
  }
}

// ---------------- output projection + residual + splits (128-tile) ----------------
// grid: x = n-tile (8), y = m-tile (33)
__global__ __launch_bounds__(256) void k_out(
    const unsigned short* __restrict__ ctxb, const unsigned short* __restrict__ Wob,
    const float* __restrict__ bo, const float* __restrict__ tokens,
    const float* __restrict__ memory, float* __restrict__ out_tok,
    unsigned short* __restrict__ tokb, unsigned short* __restrict__ tokTb,
    float* __restrict__ memout, unsigned short* __restrict__ comb) {
  f32x4 acc[4][4];
  const int m0 = blockIdx.y * 128, n0 = blockIdx.x * 128;
  gemm128_core(ctxb, Wob, D_, m0, n0, acc);
  const int tid = threadIdx.x, w = tid >> 6, l = tid & 63;
  const int wr = w >> 1, wc = w & 1;
#pragma unroll
  for (int i = 0; i < 4; i++) {
#pragma unroll
    for (int j = 0; j < 4; j++) {
#pragma unroll
      for (int r = 0; r < 4; r++) {
        int m = m0 + wr * 64 + i * 16 + (l >> 4) * 4 + r;
        int c = n0 + wc * 64 + j * 16 + (l & 15);
        int b = m / T_, t = m - b * T_;
        float xo = (t < M_) ? memory[((size_t)b * M_ + t) * D_ + c]
                            : tokens[((size_t)b * S_ + (t - M_)) * D_ + c];
        float val = acc[i][j][r] + bo[c] + xo;
        if (t < M_) {
          memout[((size_t)b * M_ + t) * D_ + c] = val;
          comb[((size_t)b * M_ + t) * (2 * D_) + c] = bf16_of(val);
        } else {
          size_t ti = (size_t)b * S_ + (t - M_);
          out_tok[ti * D_ + c] = val;
          tokb[ti * D_ + c] = bf16_of(val);
          tokTb[((size_t)b * D_ + c) * S_ + (t - M_)] = bf16_of(val);
        }
      }
    }
  }
}

// ---------------- pool scores ----------------
__global__ __launch_bounds__(256) void k_pscore(
    const unsigned short* __restrict__ pqb, const unsigned short* __restrict__ tokb,
    float* __restrict__ pscores) {
  f32x4 acc[4];
  const unsigned short* Bt = tokb + (size_t)blockIdx.z * S_ * D_;
  gemm_core(pqb, Bt, D_, 0, blockIdx.x * 64, acc);
  const int tid = threadIdx.x, w = tid >> 6, l = tid & 63;
#pragma unroll
  for (int n = 0; n < 4; n++) {
#pragma unroll
    for (int r = 0; r < 4; r++) {
      int m = w * 16 + (l >> 4) * 4 + r;
      int s = blockIdx.x * 64 + n * 16 + (l & 15);
      pscores[((size_t)blockIdx.z * M_ + m) * S_ + s] = acc[n][r];
    }
  }
}

// ---------------- pool softmax ----------------
__global__ __launch_bounds__(256) void k_psoftmax(const float* __restrict__ ps,
                                                  unsigned short* __restrict__ pw) {
  const int row = blockIdx.x;
  const float* src = ps + (size_t)row * S_;
  const int tid = threadIdx.x;
  float v[8];
  float mx = -1e30f;
#pragma unroll
  for (int i = 0; i < 8; i++) {
    v[i] = src[tid + i * 256];
    mx = fmaxf(mx, v[i]);
  }
#pragma unroll
  for (int off = 1; off < 64; off <<= 1) mx = fmaxf(mx, __shfl_xor(mx, off));
  __shared__ float rm[4], rs[4];
  if ((tid & 63) == 0) rm[tid >> 6] = mx;
  __syncthreads();
  mx = fmaxf(fmaxf(rm[0], rm[1]), fmaxf(rm[2], rm[3]));
  float sum = 0.f;
#pragma unroll
  for (int i = 0; i < 8; i++) {
    v[i] = __expf(v[i] - mx);
    sum += v[i];
  }
#pragma unroll
  for (int off = 1; off < 64; off <<= 1) sum += __shfl_xor(sum, off);
  if ((tid & 63) == 0) rs[tid >> 6] = sum;
  __syncthreads();
  float inv = 1.f / (rs[0] + rs[1] + rs[2] + rs[3]);
#pragma unroll
  for (int i = 0; i < 8; i++)
    pw[(size_t)row * S_ + tid + i * 256] = bf16_of(v[i] * inv);
}

// ---------------- summary = pweights @ tok_out -> combined[:, D:] ----------------
__global__ __launch_bounds__(256) void k_summary(
    const unsigned short* __restrict__ pw, const unsigned short* __restrict__ tokTb,
    unsigned short* __restrict__ comb) {
  f32x4 acc[4];
  const int b = blockIdx.z;
  gemm_core(pw + (size_t)b * M_ * S_, tokTb + (size_t)b * D_ * S_, S_, 0,
            blockIdx.x * 64, acc);
  const int tid = threadIdx.x, w = tid >> 6, l = tid & 63;
#pragma unroll
  for (int n = 0; n < 4; n++) {
#pragma unroll
    for (int r = 0; r < 4; r++) {
      int m = w * 16 + (l >> 4) * 4 + r;
      int c = blockIdx.x * 64 + n * 16 + (l & 15);
      comb[((size_t)b * M_ + m) * (2 * D_) + D_ + c] = bf16_of(acc[n][r]);
    }
  }
}

// ---------------- cell GEMM ----------------
__global__ __launch_bounds__(256) void k_cell(
    const unsigned short* __restrict__ comb, const unsigned short* __restrict__ cWb,
    const float* __restrict__ cb, float* __restrict__ update) {
  f32x4 acc[4];
  gemm_core(comb, cWb, 2 * D_, blockIdx.y * 64, blockIdx.x * 64, acc);
  const int tid = threadIdx.x, w = tid >> 6, l = tid & 63;
#pragma unroll
  for (int n = 0; n < 4; n++) {
#pragma unroll
    for (int r = 0; r < 4; r++) {
      int m = blockIdx.y * 64 + w * 16 + (l >> 4) * 4 + r;
      int c = blockIdx.x * 64 + n * 16 + (l & 15);
      update[(size_t)m * (2 * D_) + c] = acc[n][r] + cb[c];
    }
  }
}

// ---------------- final gating ----------------
__global__ void k_newmem(const float* __restrict__ update,
                         const float* __restrict__ memout,
                         float* __restrict__ out2) {
  int i = blockIdx.x * blockDim.x + threadIdx.x;
  if (i >= B_ * M_ * D_) return;
  int r = i >> 10, d = i & 1023;
  float g = update[(size_t)r * (2 * D_) + d];
  float c = update[(size_t)r * (2 * D_) + D_ + d];
  float sg = 1.f / (1.f + __expf(-g));
  float sc = 1.f / (1.f + __expf(-c));
  out2[i] = memout[i] * sg + (1.f - sg) * (c * sc);
}

// ---------------- launch ----------------
extern "C" void kernel_launch(void* const* d_in, const int* in_sizes, int n_in,
                              void* d_out, int out_size, void* d_ws, size_t ws_size,
                              hipStream_t stream) {
  const float* tokens = (const float*)d_in[0];
  const float* memory = (const float*)d_in[1];
  const float* Wq = (const float*)d_in[2];
  const float* bq = (const float*)d_in[3];
  const float* Wk = (const float*)d_in[4];
  const float* bk = (const float*)d_in[5];
  const float* Wv = (const float*)d_in[6];
  const float* bv = (const float*)d_in[7];
  const float* Wo = (const float*)d_in[8];
  const float* bo = (const float*)d_in[9];
  const float* pool_q = (const float*)d_in[10];
  const float* cell_W = (const float*)d_in[11];
  const float* cell_b = (const float*)d_in[12];

  size_t off = 0;
  auto alloc = [&](size_t bytes) -> void* {
    void* p = (char*)d_ws + off;
    off += (bytes + 255) & ~(size_t)255;
    return p;
  };
  unsigned short* xb    = (unsigned short*)alloc((size_t)BT_ * D_ * 2);
  unsigned short* Wqb   = (unsigned short*)alloc((size_t)D_ * D_ * 2);
  unsigned short* Wkb   = (unsigned short*)alloc((size_t)D_ * D_ * 2);
  unsigned short* Wvb   = (unsigned short*)alloc((size_t)D_ * D_ * 2);
  unsigned short* Wob   = (unsigned short*)alloc((size_t)D_ * D_ * 2);
  unsigned short* cWb   = (unsigned short*)alloc((size_t)(2 * D_) * (2 * D_) * 2);
  unsigned short* pqb   = (unsigned short*)alloc((size_t)M_ * D_ * 2);
  unsigned short* qg    = (unsigned short*)alloc((size_t)B_ * H_ * T_ * HD_ * 2);
  unsigned short* kg    = (unsigned short*)alloc((size_t)B_ * H_ * T_ * HD_ * 2);
  unsigned short* vTg   = (unsigned short*)alloc((size_t)B_ * H_ * HD_ * T_ * 2);
  unsigned short* ctxb  = (unsigned short*)alloc((size_t)BT_ * D_ * 2);
  unsigned short* tokb  = (unsigned short*)alloc((size_t)B_ * S_ * D_ * 2);
  unsigned short* tokTb = (unsigned short*)alloc((size_t)B_ * D_ * S_ * 2);
  float*          memout= (float*)alloc((size_t)B_ * M_ * D_ * 4);
  unsigned short* comb  = (unsigned short*)alloc((size_t)B_ * M_ * 2 * D_ * 2);
  float*          pscor = (float*)alloc((size_t)B_ * M_ * S_ * 4);
  unsigned short* pwt   = (unsigned short*)alloc((size_t)B_ * M_ * S_ * 2);
  float*          upd   = (float*)alloc((size_t)B_ * M_ * 2 * D_ * 4);

  float* out_tok = (float*)d_out;
  float* out_mem = out_tok + (size_t)B_ * S_ * D_;

  k_build_x<<<2048, 256, 0, stream>>>(tokens, memory, xb);
  k_cast_all<<<4096, 256, 0, stream>>>(Wq, Wk, Wv, Wo, cell_W, pool_q,
                                       Wqb, Wkb, Wvb, Wob, cWb, pqb);

  k_qkv<<<dim3(8, 33, 3), 256, 0, stream>>>(xb, Wqb, Wkb, Wvb, bq, bk, bv, qg, kg, vTg);
  k_attn<<<dim3(33, 32), 256, 0, stream>>>(qg, kg, vTg, ctxb);
  k_out<<<dim3(8, 33), 256, 0, stream>>>(ctxb, Wob, bo, tokens, memory, out_tok,
                                         tokb, tokTb, memout, comb);
  k_pscore<<<dim3(32, 1, 2), 256, 0, stream>>>(pqb, tokb, pscor);
  k_psoftmax<<<B_ * M_, 256, 0, stream>>>(pscor, pwt);
  k_summary<<<dim3(16, 1, 2), 256, 0, stream>>>(pwt, tokTb, comb);
  k_cell<<<dim3(32, 2), 256, 0, stream>>>(comb, cWb, cell_b, upd);
  k_newmem<<<512, 256, 0, stream>>>(upd, memout, out_mem);
}